// Round 1
// baseline (135.677 us; speedup 1.0000x reference)
//
#include <hip/hip_runtime.h>
#include <hip/hip_fp16.h>
#include <math.h>

#define B_ 4
#define K_ 4
#define D_ 96
#define L_ 2048
#define N_ 16
#define R_ 6
#define C_ 38          // R + 2N
#define CH 16          // l's per thread in scan
#define TPR 128        // chunk owners = L_/CH (BC layout constant AND scan block size)

__device__ __forceinline__ float softplus_f(float x) {
    return fmaxf(x, 0.f) + __logf(1.f + __expf(-fabsf(x)));
}

#if __has_builtin(__builtin_amdgcn_exp2f)
__device__ __forceinline__ float exp2_fast(float x) { return __builtin_amdgcn_exp2f(x); }
#else
__device__ __forceinline__ float exp2_fast(float x) { return __expf(0.6931471805599453f * x); }
#endif

__device__ __forceinline__ float h2f(const uint4& v, int e) {
    return __half2float(((const __half*)&v)[e]);
}

// BC layout (fp16, chunk-interleaved for CH=16 wave-coalesced scan reads):
//   uint4 (=8 halfs) at index (((bk*16 + i)*4 + j)*128 + t), where l = t*16+i
//   j=0: B n0..7   j=1: B n8..15   j=2: C n0..7   j=3: C n8..15

// ---------------------------------------------------------------------------
// Proj v2: 2 c-groups instead of 6 -> xs HBM traffic 75MB -> 25MB.
//   cg=0: 16 B-rows (c = R..R+15) + 6 dt-rows (c = 0..5)  -> 22 live accs
//   cg=1: 16 C-rows (c = R+16..R+31)                      -> 16 live accs
// grid (B*K, 8, 2) = 256 blocks (1/CU), block 256, one l per thread.
// ---------------------------------------------------------------------------
__global__ __launch_bounds__(256) void proj_kernel(
    const float* __restrict__ xs, const float* __restrict__ xpw,
    uint4* __restrict__ BCc, float* __restrict__ dts_ws)
{
    __shared__ float sWt[D_][24];
    const int bk = blockIdx.x;
    const int k = bk & 3;
    const int cg = blockIdx.z;
    const int tid = threadIdx.x;

    for (int idx = tid; idx < 24 * D_; idx += 256) {
        const int m = idx / D_, dd = idx % D_;   // coalesced over dd
        float wv = 0.f;
        if (cg == 0) {
            if (m < 16)      wv = xpw[(k * C_ + R_ + m) * D_ + dd];        // B rows
            else if (m < 22) wv = xpw[(k * C_ + (m - 16)) * D_ + dd];      // dt rows
        } else {
            if (m < 16)      wv = xpw[(k * C_ + R_ + 16 + m) * D_ + dd];   // C rows
        }
        sWt[dd][m] = wv;
    }
    __syncthreads();

    const int l = blockIdx.y * 256 + tid;
    const float* Xl = xs + (size_t)bk * D_ * L_ + l;

    float acc[24];
#pragma unroll
    for (int m = 0; m < 24; ++m) acc[m] = 0.f;

#pragma unroll
    for (int d = 0; d < D_; ++d) {
        const float xv = Xl[d * L_];
#pragma unroll
        for (int q = 0; q < 6; ++q) {
            const float4 w = *(const float4*)&sWt[d][q * 4];
            acc[q * 4 + 0] = fmaf(w.x, xv, acc[q * 4 + 0]);
            acc[q * 4 + 1] = fmaf(w.y, xv, acc[q * 4 + 1]);
            acc[q * 4 + 2] = fmaf(w.z, xv, acc[q * 4 + 2]);
            acc[q * 4 + 3] = fmaf(w.w, xv, acc[q * 4 + 3]);
        }
    }

    const int i8 = l & 15, t8 = l >> 4;
    const int jb = cg * 2;                     // cg0 -> j=0,1 (B); cg1 -> j=2,3 (C)
    union { __half h[8]; uint4 v; } p0, p1;
#pragma unroll
    for (int e = 0; e < 8; ++e) {
        p0.h[e] = __float2half(acc[e]);
        p1.h[e] = __float2half(acc[8 + e]);
    }
    BCc[(((size_t)bk * 16 + i8) * 4 + jb) * TPR + t8] = p0.v;
    BCc[(((size_t)bk * 16 + i8) * 4 + jb + 1) * TPR + t8] = p1.v;

    if (cg == 0) {
#pragma unroll
        for (int r = 0; r < R_; ++r)
            dts_ws[((size_t)bk * R_ + r) * L_ + l] = acc[16 + r];
    }
}

// ---------------------------------------------------------------------------
// Scan v2: block = 128 threads (2 waves), each thread owns ALL 16 n's for its
// 16-l chunk. Removes the g=0/g=1 duplication of del/x/softplus, the sy
// combine + final barrier, and gives 6 blocks/CU residency (1536 = 6*256,
// zero dispatch tail) at ~12 waves/CU.
// ---------------------------------------------------------------------------
__global__ __launch_bounds__(128) void scan_kernel(
    const float* __restrict__ xs, const float* __restrict__ A_logs,
    const float* __restrict__ Ds, const float* __restrict__ dtw,
    const float* __restrict__ dtb, const float* __restrict__ dts_ws,
    const uint4* __restrict__ BCc, float* __restrict__ out)
{
    __shared__ float sBw[16];        // wave0 inclusive b-aggregate

    const int bkd = blockIdx.x;
    const int d = bkd % D_;
    const int bk = bkd / D_;
    const int k = bk & 3;
    const int kd = k * D_ + d;
    const int t = threadIdx.x;       // 0..127: chunk owner, l in [t*16, t*16+16)
    const int lane = t & 63;
    const int w = t >> 6;            // wave 0/1

    const uint4* BC = BCc + (size_t)bk * 16 * 4 * TPR;

    // xs chunk -> registers (4x float4)
    const float4* xv4 = (const float4*)(xs + (size_t)bkd * L_);
    float x[CH];
#pragma unroll
    for (int q = 0; q < 4; ++q)
        *(float4*)&x[q * 4] = xv4[t * 4 + q];

    // delta chunk (computed exactly once per (bkd, chunk) now)
    float del[CH];
    const float bias = dtb[kd];
#pragma unroll
    for (int j = 0; j < CH; ++j) del[j] = bias;
    const float* w2 = dtw + (size_t)kd * R_;
    const float4* dts4 = (const float4*)(dts_ws + (size_t)bk * R_ * L_);
#pragma unroll
    for (int r = 0; r < R_; ++r) {
        const float wr = w2[r];
#pragma unroll
        for (int q = 0; q < 4; ++q) {
            const float4 tv = dts4[r * (L_ / 4) + t * 4 + q];
            del[q * 4 + 0] = fmaf(wr, tv.x, del[q * 4 + 0]);
            del[q * 4 + 1] = fmaf(wr, tv.y, del[q * 4 + 1]);
            del[q * 4 + 2] = fmaf(wr, tv.z, del[q * 4 + 2]);
            del[q * 4 + 3] = fmaf(wr, tv.w, del[q * 4 + 3]);
        }
    }
#pragma unroll
    for (int j = 0; j < CH; ++j) del[j] = softplus_f(del[j]);

    float A2[16];
    const float* Ap = A_logs + (size_t)kd * N_;
#pragma unroll
    for (int n = 0; n < 16; ++n) A2[n] = -__expf(Ap[n]) * 1.44269504f;
    const float Dval = Ds[kd];

    // Phase 1: per-chunk aggregate over all 16 n
    float a[16], b[16];
#pragma unroll
    for (int n = 0; n < 16; ++n) { a[n] = 1.f; b[n] = 0.f; }
#pragma unroll
    for (int i = 0; i < CH; ++i) {
        const uint4 cB0 = BC[(i * 4 + 0) * TPR + t];
        const uint4 cB1 = BC[(i * 4 + 1) * TPR + t];
        const float dl = del[i];
        const float dx = dl * x[i];
#pragma unroll
        for (int n = 0; n < 8; ++n) {
            const float dA0 = exp2_fast(dl * A2[n]);
            b[n] = fmaf(dA0, b[n], dx * h2f(cB0, n));
            a[n] *= dA0;
            const float dA1 = exp2_fast(dl * A2[8 + n]);
            b[8 + n] = fmaf(dA1, b[8 + n], dx * h2f(cB1, n));
            a[8 + n] *= dA1;
        }
    }

    // Phase 2a: wave-level inclusive scan (16 n)
#pragma unroll
    for (int off = 1; off < 64; off <<= 1) {
#pragma unroll
        for (int n = 0; n < 16; ++n) {
            const float pa = __shfl_up(a[n], off, 64);
            const float pb = __shfl_up(b[n], off, 64);
            if (lane >= off) {
                b[n] = fmaf(a[n], pb, b[n]);
                a[n] *= pa;
            }
        }
    }
    // Phase 2b: wave0 publishes its block aggregate for wave1
    if (t == 63) {
#pragma unroll
        for (int n = 0; n < 16; ++n) sBw[n] = b[n];
    }
    __syncthreads();

    // h0 = state entering this thread's chunk (exclusive scan + wave carry)
    float h[16];
#pragma unroll
    for (int n = 0; n < 16; ++n) {
        float ae = __shfl_up(a[n], 1, 64);
        float be = __shfl_up(b[n], 1, 64);
        if (lane == 0) { ae = 1.f; be = 0.f; }
        const float wb = w ? sBw[n] : 0.f;
        h[n] = fmaf(ae, wb, be);
    }

    // Phase 3: re-run chunk with true initial state; full y per thread
    float yv[CH];
#pragma unroll
    for (int i = 0; i < CH; ++i) {
        const uint4 cB0 = BC[(i * 4 + 0) * TPR + t];
        const uint4 cB1 = BC[(i * 4 + 1) * TPR + t];
        const uint4 cC0 = BC[(i * 4 + 2) * TPR + t];
        const uint4 cC1 = BC[(i * 4 + 3) * TPR + t];
        const float dl = del[i];
        const float dx = dl * x[i];
        float y = Dval * x[i];
#pragma unroll
        for (int n = 0; n < 8; ++n) {
            const float dA0 = exp2_fast(dl * A2[n]);
            h[n] = fmaf(dA0, h[n], dx * h2f(cB0, n));
            y = fmaf(h[n], h2f(cC0, n), y);
            const float dA1 = exp2_fast(dl * A2[8 + n]);
            h[8 + n] = fmaf(dA1, h[8 + n], dx * h2f(cB1, n));
            y = fmaf(h[8 + n], h2f(cC1, n), y);
        }
        yv[i] = y;
    }

    float4* ov = (float4*)(out + (size_t)bkd * L_);
#pragma unroll
    for (int q = 0; q < 4; ++q)
        ov[t * 4 + q] = make_float4(yv[q * 4], yv[q * 4 + 1],
                                    yv[q * 4 + 2], yv[q * 4 + 3]);
}

extern "C" void kernel_launch(void* const* d_in, const int* in_sizes, int n_in,
                              void* d_out, int out_size, void* d_ws, size_t ws_size,
                              hipStream_t stream) {
    const float* xs = (const float*)d_in[0];       // (B,K,D,L)
    const float* A_logs = (const float*)d_in[1];   // (K*D, N)
    const float* Ds = (const float*)d_in[2];       // (K*D,)
    const float* dtw = (const float*)d_in[3];      // (K,D,R)
    const float* dtb = (const float*)d_in[4];      // (K,D)
    const float* xpw = (const float*)d_in[5];      // (K,C,D)
    float* out = (float*)d_out;                    // (B,K,D,L) fp32

    uint4* BCc = (uint4*)d_ws;                     // 16*16*4*128 uint4 = 2 MB
    float* dts_ws = (float*)(BCc + (size_t)B_ * K_ * 16 * 4 * TPR);  // 768 KB

    proj_kernel<<<dim3(B_ * K_, 8, 2), 256, 0, stream>>>(xs, xpw, BCc, dts_ws);
    scan_kernel<<<B_ * K_ * D_, TPR, 0, stream>>>(
        xs, A_logs, Ds, dtw, dtb, dts_ws, BCc, out);
}

// Round 2
// 114.800 us; speedup vs baseline: 1.1819x; 1.1819x over previous
//
#include <hip/hip_runtime.h>
#include <hip/hip_fp16.h>
#include <math.h>

#define B_ 4
#define K_ 4
#define D_ 96
#define L_ 2048
#define N_ 16
#define R_ 6
#define C_ 38          // R + 2N
#define CH 16          // l's per thread in scan (measured optimum: 8->52us, 16->40us, 32->84us)
#define TPR 128        // threads per row = L_/CH

__device__ __forceinline__ float softplus_f(float x) {
    return fmaxf(x, 0.f) + __logf(1.f + __expf(-fabsf(x)));
}

#if __has_builtin(__builtin_amdgcn_exp2f)
__device__ __forceinline__ float exp2_fast(float x) { return __builtin_amdgcn_exp2f(x); }
#else
__device__ __forceinline__ float exp2_fast(float x) { return __expf(0.6931471805599453f * x); }
#endif

__device__ __forceinline__ float h2f(const uint4& v, int e) {
    return __half2float(((const __half*)&v)[e]);
}

// BC layout (fp16, chunk-interleaved for CH=16 wave-coalesced scan reads):
//   uint4 (=8 halfs) at index (((bk*16 + i)*4 + j)*128 + t), where l = t*16+i
//   j=0: B n0..7   j=1: B n8..15   j=2: C n0..7   j=3: C n8..15

// ---------------------------------------------------------------------------
// Proj v3: 4-way d-split for occupancy (proj is latency-bound, not BW-bound:
// xs is L2/LLC-resident). Block 256 = 4 d-groups x 64 l's; each thread
// accumulates 24 d's for all 24 outputs, LDS-combine, dg==0 stores.
// grid (B*K, 32, 2) = 1024 blocks -> 4 blocks/CU, 16 waves/CU (vs 4 in v2).
//   cg=0: 16 B-rows (c = R..R+15) + 6 dt-rows (c = 0..5)
//   cg=1: 16 C-rows (c = R+16..R+31)
// ---------------------------------------------------------------------------
__global__ __launch_bounds__(256) void proj_kernel(
    const float* __restrict__ xs, const float* __restrict__ xpw,
    uint4* __restrict__ BCc, float* __restrict__ dts_ws)
{
    __shared__ float sWt[D_][24];
    __shared__ float sRed[3][64][25];   // partials from dg=1..3; stride 25 = conflict-free
    const int bk = blockIdx.x;
    const int k = bk & 3;
    const int cg = blockIdx.z;
    const int tid = threadIdx.x;
    const int dg = tid >> 6;            // d-group 0..3 (24 d's each)
    const int li = tid & 63;            // l within block

    for (int idx = tid; idx < 24 * D_; idx += 256) {
        const int m = idx / D_, dd = idx % D_;   // coalesced over dd
        float wv = 0.f;
        if (cg == 0) {
            if (m < 16)      wv = xpw[(k * C_ + R_ + m) * D_ + dd];        // B rows
            else if (m < 22) wv = xpw[(k * C_ + (m - 16)) * D_ + dd];      // dt rows
        } else {
            if (m < 16)      wv = xpw[(k * C_ + R_ + 16 + m) * D_ + dd];   // C rows
        }
        sWt[dd][m] = wv;
    }
    __syncthreads();

    const int l = blockIdx.y * 64 + li;
    const float* Xl = xs + (size_t)bk * D_ * L_ + l;

    float acc[24];
#pragma unroll
    for (int m = 0; m < 24; ++m) acc[m] = 0.f;

#pragma unroll
    for (int dd = 0; dd < 24; ++dd) {
        const int d = dg * 24 + dd;
        const float xv = Xl[(size_t)d * L_];
#pragma unroll
        for (int q = 0; q < 6; ++q) {
            const float4 w = *(const float4*)&sWt[d][q * 4];  // broadcast within dg
            acc[q * 4 + 0] = fmaf(w.x, xv, acc[q * 4 + 0]);
            acc[q * 4 + 1] = fmaf(w.y, xv, acc[q * 4 + 1]);
            acc[q * 4 + 2] = fmaf(w.z, xv, acc[q * 4 + 2]);
            acc[q * 4 + 3] = fmaf(w.w, xv, acc[q * 4 + 3]);
        }
    }

    if (dg > 0) {
#pragma unroll
        for (int m = 0; m < 24; ++m) sRed[dg - 1][li][m] = acc[m];
    }
    __syncthreads();
    if (dg == 0) {
#pragma unroll
        for (int m = 0; m < 24; ++m)
            acc[m] += sRed[0][li][m] + sRed[1][li][m] + sRed[2][li][m];

        const int i8 = l & 15, t8 = l >> 4;
        const int jb = cg * 2;                 // cg0 -> j=0,1 (B); cg1 -> j=2,3 (C)
        union { __half h[8]; uint4 v; } p0, p1;
#pragma unroll
        for (int e = 0; e < 8; ++e) {
            p0.h[e] = __float2half(acc[e]);
            p1.h[e] = __float2half(acc[8 + e]);
        }
        BCc[(((size_t)bk * 16 + i8) * 4 + jb) * TPR + t8] = p0.v;
        BCc[(((size_t)bk * 16 + i8) * 4 + jb + 1) * TPR + t8] = p1.v;

        if (cg == 0) {
#pragma unroll
            for (int r = 0; r < R_; ++r)
                dts_ws[((size_t)bk * R_ + r) * L_ + l] = acc[16 + r];
        }
    }
}

// ---------------------------------------------------------------------------
// Scan (R12 verbatim — round-0 known-good ~40us): grid B*K*D, block 256 =
// 2 n-groups x 128 l-threads. Group g = tid>>7 owns n in [8g, 8g+8);
// t = tid&127 owns l in [t*16, t*16+16). Natural register allocation.
// ---------------------------------------------------------------------------
__global__ __launch_bounds__(256) void scan_kernel(
    const float* __restrict__ xs, const float* __restrict__ A_logs,
    const float* __restrict__ Ds, const float* __restrict__ dtw,
    const float* __restrict__ dtb, const float* __restrict__ dts_ws,
    const uint4* __restrict__ BCc, float* __restrict__ out)
{
    __shared__ float sAw[4][8];
    __shared__ float sBw[4][8];
    __shared__ float sy[TPR][17];   // stride 17: worst 2-way conflict = free

    const int bkd = blockIdx.x;
    const int d = bkd % D_;
    const int bk = bkd / D_;
    const int k = bk & 3;
    const int kd = k * D_ + d;
    const int tid = threadIdx.x;
    const int g = tid >> 7;          // n-half 0/1
    const int t = tid & (TPR - 1);   // l-chunk owner
    const int lane = tid & 63;
    const int gw = tid >> 6;         // wave 0..3; group g owns waves 2g, 2g+1

    const uint4* BC = BCc + (size_t)bk * 16 * 4 * TPR;
    const int jB = g, jC = 2 + g;

    // xs chunk -> registers (4x float4)
    const float4* xv4 = (const float4*)(xs + (size_t)bkd * L_);
    float x[CH];
#pragma unroll
    for (int q = 0; q < 4; ++q)
        *(float4*)&x[q * 4] = xv4[t * 4 + q];

    // delta chunk
    float del[CH];
    const float bias = dtb[kd];
#pragma unroll
    for (int j = 0; j < CH; ++j) del[j] = bias;
    const float* w2 = dtw + (size_t)kd * R_;
    const float4* dts4 = (const float4*)(dts_ws + (size_t)bk * R_ * L_);
#pragma unroll
    for (int r = 0; r < R_; ++r) {
        const float wr = w2[r];
#pragma unroll
        for (int q = 0; q < 4; ++q) {
            const float4 tv = dts4[r * (L_ / 4) + t * 4 + q];
            del[q * 4 + 0] = fmaf(wr, tv.x, del[q * 4 + 0]);
            del[q * 4 + 1] = fmaf(wr, tv.y, del[q * 4 + 1]);
            del[q * 4 + 2] = fmaf(wr, tv.z, del[q * 4 + 2]);
            del[q * 4 + 3] = fmaf(wr, tv.w, del[q * 4 + 3]);
        }
    }
#pragma unroll
    for (int j = 0; j < CH; ++j) del[j] = softplus_f(del[j]);

    float A2[8];
    const float* Ap = A_logs + (size_t)kd * N_ + g * 8;
#pragma unroll
    for (int n = 0; n < 8; ++n) A2[n] = -__expf(Ap[n]) * 1.44269504f;
    const float Dval = Ds[kd];

    // Phase 1: per-chunk aggregate over this n-half
    float a[8], b[8];
#pragma unroll
    for (int n = 0; n < 8; ++n) { a[n] = 1.f; b[n] = 0.f; }
#pragma unroll
    for (int i = 0; i < CH; ++i) {
        const uint4 cB = BC[(i * 4 + jB) * TPR + t];
        const float dl = del[i];
        const float dx = dl * x[i];
#pragma unroll
        for (int n = 0; n < 8; ++n) {
            const float dA = exp2_fast(dl * A2[n]);
            b[n] = fmaf(dA, b[n], dx * h2f(cB, n));
            a[n] *= dA;
        }
    }

    // Phase 2a: wave-level inclusive scan (8 n's)
#pragma unroll
    for (int off = 1; off < 64; off <<= 1) {
#pragma unroll
        for (int n = 0; n < 8; ++n) {
            const float pa = __shfl_up(a[n], off, 64);
            const float pb = __shfl_up(b[n], off, 64);
            if (lane >= off) {
                b[n] = fmaf(a[n], pb, b[n]);
                a[n] *= pa;
            }
        }
    }
    // Phase 2b: cross-wave fixup (2 waves per group)
    if (lane == 63) {
#pragma unroll
        for (int n = 0; n < 8; ++n) { sAw[gw][n] = a[n]; sBw[gw][n] = b[n]; }
    }
    __syncthreads();

    // h0 = state entering this thread's chunk
    float h[8];
#pragma unroll
    for (int n = 0; n < 8; ++n) {
        float ae = __shfl_up(a[n], 1, 64);
        float be = __shfl_up(b[n], 1, 64);
        if (lane == 0) { ae = 1.f; be = 0.f; }
        float wb = 0.f;
        for (int w = g * 2; w < gw; ++w) wb = fmaf(sAw[w][n], wb, sBw[w][n]);
        h[n] = fmaf(ae, wb, be);
    }

    // Phase 3: re-run chunk with true initial state; partial y per group
    float yv[CH];
#pragma unroll
    for (int i = 0; i < CH; ++i) {
        const uint4 cB = BC[(i * 4 + jB) * TPR + t];
        const uint4 cC = BC[(i * 4 + jC) * TPR + t];
        const float dl = del[i];
        const float dx = dl * x[i];
        float y = (g == 0) ? Dval * x[i] : 0.f;
#pragma unroll
        for (int n = 0; n < 8; ++n) {
            const float dA = exp2_fast(dl * A2[n]);
            h[n] = fmaf(dA, h[n], dx * h2f(cB, n));
            y = fmaf(h[n], h2f(cC, n), y);
        }
        yv[i] = y;
    }

    // Combine group partials and store
    if (g == 1) {
#pragma unroll
        for (int j = 0; j < CH; ++j) sy[t][j] = yv[j];
    }
    __syncthreads();
    if (g == 0) {
#pragma unroll
        for (int j = 0; j < CH; ++j) yv[j] += sy[t][j];
        float4* ov = (float4*)(out + (size_t)bkd * L_);
#pragma unroll
        for (int q = 0; q < 4; ++q)
            ov[t * 4 + q] = make_float4(yv[q * 4], yv[q * 4 + 1],
                                        yv[q * 4 + 2], yv[q * 4 + 3]);
    }
}

extern "C" void kernel_launch(void* const* d_in, const int* in_sizes, int n_in,
                              void* d_out, int out_size, void* d_ws, size_t ws_size,
                              hipStream_t stream) {
    const float* xs = (const float*)d_in[0];       // (B,K,D,L)
    const float* A_logs = (const float*)d_in[1];   // (K*D, N)
    const float* Ds = (const float*)d_in[2];       // (K*D,)
    const float* dtw = (const float*)d_in[3];      // (K,D,R)
    const float* dtb = (const float*)d_in[4];      // (K,D)
    const float* xpw = (const float*)d_in[5];      // (K,C,D)
    float* out = (float*)d_out;                    // (B,K,D,L) fp32

    uint4* BCc = (uint4*)d_ws;                     // 16*16*4*128 uint4 = 2 MB
    float* dts_ws = (float*)(BCc + (size_t)B_ * K_ * 16 * 4 * TPR);  // 768 KB

    proj_kernel<<<dim3(B_ * K_, 32, 2), 256, 0, stream>>>(xs, xpw, BCc, dts_ws);
    scan_kernel<<<B_ * K_ * D_, 256, 0, stream>>>(
        xs, A_logs, Ds, dtw, dtb, dts_ws, BCc, out);
}